// Round 10
// baseline (497.196 us; speedup 1.0000x reference)
//
#include <hip/hip_runtime.h>
#include <math.h>

#define NG 64   // graphs

typedef short bf16x8 __attribute__((ext_vector_type(8)));
typedef short bf16x4 __attribute__((ext_vector_type(4)));
typedef float f32x4 __attribute__((ext_vector_type(4)));

#define LOG2E 1.4426950408889634f

static inline int cdiv(int a, int b) { return (a + b - 1) / b; }

__device__ inline ushort f2b(float f) {
  union { float f; uint u; } v; v.f = f;
  uint u = v.u;
  return (ushort)((u + 0x7fffu + ((u >> 16) & 1u)) >> 16);
}
__device__ inline float b2f(ushort h) {
  union { uint u; float f; } v; v.u = ((uint)h) << 16;
  return v.f;
}

__device__ __forceinline__ void unpack8(bf16x8 vb, float* v) {
  union { bf16x8 b; uint u[4]; } cv; cv.b = vb;
#pragma unroll
  for (int q = 0; q < 4; ++q) {
    union { uint u; float f; } lo, hi;
    lo.u = cv.u[q] << 16;
    hi.u = cv.u[q] & 0xffff0000u;
    v[2 * q] = lo.f; v[2 * q + 1] = hi.f;
  }
}
__device__ __forceinline__ void unpack4(bf16x4 vb, float* v) {
  union { bf16x4 b; uint u[2]; } cv; cv.b = vb;
#pragma unroll
  for (int q = 0; q < 2; ++q) {
    union { uint u; float f; } lo, hi;
    lo.u = cv.u[q] << 16;
    hi.u = cv.u[q] & 0xffff0000u;
    v[2 * q] = lo.f; v[2 * q + 1] = hi.f;
  }
}

// pure-VALU all-reduce (sum) within each 16-lane row via DPP row_ror
__device__ __forceinline__ float dppsum16(float x) {
  union { float f; int i; } a, b;
  a.f = x;
  b.i = __builtin_amdgcn_update_dpp(0, a.i, 0x121, 0xF, 0xF, true); a.f += b.f; // ror:1
  b.i = __builtin_amdgcn_update_dpp(0, a.i, 0x122, 0xF, 0xF, true); a.f += b.f; // ror:2
  b.i = __builtin_amdgcn_update_dpp(0, a.i, 0x124, 0xF, 0xF, true); a.f += b.f; // ror:4
  b.i = __builtin_amdgcn_update_dpp(0, a.i, 0x128, 0xF, 0xF, true); a.f += b.f; // ror:8
  return a.f;
}

// ---------------- fused prep: features + both weight transposes + degree hist ----------------
__global__ __launch_bounds__(256) void k_prep(
    const float* __restrict__ xc, const int* __restrict__ xcl,
    const int* __restrict__ xpi, const float* __restrict__ ctab,
    const float* __restrict__ ptab,
    const float* __restrict__ Wl1, const float* __restrict__ Wr1,
    const float* __restrict__ Wl2, const float* __restrict__ Wr2,
    const int* __restrict__ edst,
    ushort* __restrict__ xb, ushort* __restrict__ W1t, ushort* __restrict__ W2t,
    int* __restrict__ deg, int n, int E) {
  int t = blockIdx.x * blockDim.x + threadIdx.x;
  int T1 = n * 160;
  int T2 = T1 + 1024 * 160;
  int T3 = T2 + 512 * 512;
  int T4 = T3 + E + n;
  if (t < T1) {
    int node = t / 160, c = t % 160;
    float v;
    if (c < 6)        v = xc[node * 6 + c];
    else if (c < 70)  v = ctab[xcl[node] * 64 + (c - 6)];
    else if (c < 134) v = ptab[xpi[node] * 64 + (c - 70)];
    else              v = 0.f;
    xb[t] = f2b(v);
  } else if (t < T2) {
    int u = t - T1;
    int c = u / 160, k = u % 160;
    float v = 0.f;
    if (k < 134) v = (c < 512) ? Wl1[k * 512 + c] : Wr1[k * 512 + (c - 512)];
    W1t[u] = f2b(v);
  } else if (t < T3) {
    int u = t - T2;
    int c = u / 512, k = u % 512;
    float v = (c < 256) ? Wl2[k * 256 + c] : Wr2[k * 256 + (c - 256)];
    W2t[u] = f2b(v);
  } else if (t < T4) {
    int u = t - T3;
    if (u < E) atomicAdd(&deg[edst[u]], 1);
    else atomicAdd(&deg[u - E], 1);   // self loops
  }
}

// 3-phase scan
__global__ __launch_bounds__(256) void k_bsum(const int* __restrict__ deg,
                                              int* __restrict__ bsum, int n) {
  int i = blockIdx.x * 256 + threadIdx.x;
  int v = (i < n) ? deg[i] : 0;
#pragma unroll
  for (int off = 1; off < 64; off <<= 1) v += __shfl_xor(v, off);
  __shared__ int ws[4];
  if ((threadIdx.x & 63) == 0) ws[threadIdx.x >> 6] = v;
  __syncthreads();
  if (threadIdx.x == 0) bsum[blockIdx.x] = ws[0] + ws[1] + ws[2] + ws[3];
}

__global__ __launch_bounds__(256) void k_scanb(const int* __restrict__ bsum,
                                               int* __restrict__ boff, int nb) {
  int t = threadIdx.x, lane = t & 63;
  int v = (t < nb) ? bsum[t] : 0;
  int incl = v;
#pragma unroll
  for (int off = 1; off < 64; off <<= 1) {
    int u = __shfl_up(incl, off);
    if (lane >= off) incl += u;
  }
  __shared__ int wsum[4];
  if (lane == 63) wsum[t >> 6] = incl;
  __syncthreads();
  int add = 0;
  for (int w = 0; w < (t >> 6); ++w) add += wsum[w];
  if (t < nb) boff[t] = incl + add - v;  // exclusive
}

__global__ __launch_bounds__(256) void k_scanc(const int* __restrict__ deg,
                                               const int* __restrict__ boff,
                                               int* __restrict__ rowptr, int n) {
  int b = blockIdx.x, t = threadIdx.x, lane = t & 63;
  int i = b * 256 + t;
  int v = (i < n) ? deg[i] : 0;
  int incl = v;
#pragma unroll
  for (int off = 1; off < 64; off <<= 1) {
    int u = __shfl_up(incl, off);
    if (lane >= off) incl += u;
  }
  __shared__ int wsum[4];
  if (lane == 63) wsum[t >> 6] = incl;
  __syncthreads();
  int add = boff[b];
  for (int w = 0; w < (t >> 6); ++w) add += wsum[w];
  if (i < n) rowptr[i + 1] = incl + add;
  if (i == 0) rowptr[0] = 0;
}

__global__ __launch_bounds__(256) void k_scatter(
    const int* __restrict__ src, const int* __restrict__ dst,
    const int* __restrict__ rowptr, int* __restrict__ fill,
    int* __restrict__ csr, int E, int N) {
  int t = blockIdx.x * blockDim.x + threadIdx.x;
  int s, d;
  if (t < E) { s = src[t]; d = dst[t]; }
  else if (t < E + N) { s = t - E; d = t - E; }
  else if (t < E + N + 8) { csr[t] = 0; return; }
  else return;
  int pos = rowptr[d] + atomicAdd(&fill[d], 1);
  csr[pos] = s;
}

// ---------------- bf16 MFMA GEMM with SPLIT output: cols<nhalf -> Clo, else Chi ----------------
#define GBM 128
#define GBN 128
#define GBK 32
#define ESTRIDE 136
__device__ __forceinline__ int swzf(int r, int s) {
  return r * 64 + ((s * 16) ^ (((r >> 1) & 3) << 4));
}
__global__ __launch_bounds__(256) void k_gemm_mfma(
    const ushort* __restrict__ A, const ushort* __restrict__ Bt,
    const float* __restrict__ blo, const float* __restrict__ bhi, int nhalf,
    ushort* __restrict__ Clo, ushort* __restrict__ Chi, int M, int Kp) {
  __shared__ ushort smem[GBM * ESTRIDE];
  ushort* sA = smem;
  ushort* sB = smem + GBM * GBK;
  int tid = threadIdx.x;
  int lane = tid & 63, w = tid >> 6;
  int wr = w >> 1, wc = w & 1;
  int row0 = blockIdx.x * GBM, col0 = blockIdx.y * GBN;
  int nK = Kp / GBK;

  int rs = tid >> 2, ss = tid & 3;
  int wO0 = swzf(rs, ss);
  int wO1 = swzf(rs + 64, ss);
  bool okA0 = (row0 + rs) < M;
  bool okA1 = (row0 + rs + 64) < M;
  size_t baseA0 = (size_t)(row0 + rs) * Kp + ss * 8;
  size_t baseA1 = (size_t)(row0 + rs + 64) * Kp + ss * 8;
  size_t baseB0 = (size_t)(col0 + rs) * Kp + ss * 8;
  size_t baseB1 = (size_t)(col0 + rs + 64) * Kp + ss * 8;

  int fr = lane & 15, kq = lane >> 4;
  int aoff[4], boff[4];
#pragma unroll
  for (int m = 0; m < 4; ++m) {
    int ra = wr * 64 + m * 16 + fr;
    aoff[m] = ra * 64 + ((kq * 16) ^ (((ra >> 1) & 3) << 4));
    int rb = wc * 64 + m * 16 + fr;
    boff[m] = rb * 64 + ((kq * 16) ^ (((rb >> 1) & 3) << 4));
  }

  f32x4 acc[4][4] = {};
  bf16x8 zz = {};
  bf16x8 pa0, pa1, pb0, pb1, qa0, qa1, qb0, qb1;

#define LOADG(KS, RA0, RA1, RB0, RB1)                                   \
  do {                                                                  \
    const ushort* ap = A + (size_t)(KS) * GBK;                          \
    const ushort* bp = Bt + (size_t)(KS) * GBK;                         \
    RA0 = okA0 ? *(const bf16x8*)(ap + baseA0) : zz;                    \
    RA1 = okA1 ? *(const bf16x8*)(ap + baseA1) : zz;                    \
    RB0 = *(const bf16x8*)(bp + baseB0);                                \
    RB1 = *(const bf16x8*)(bp + baseB1);                                \
  } while (0)

#define STAGE(RA0, RA1, RB0, RB1)                                       \
  do {                                                                  \
    *(bf16x8*)((char*)sA + wO0) = RA0;                                  \
    *(bf16x8*)((char*)sA + wO1) = RA1;                                  \
    *(bf16x8*)((char*)sB + wO0) = RB0;                                  \
    *(bf16x8*)((char*)sB + wO1) = RB1;                                  \
  } while (0)

#define COMPUTE()                                                       \
  do {                                                                  \
    bf16x8 av[4], bv[4];                                                \
    _Pragma("unroll") for (int m = 0; m < 4; ++m)                       \
        av[m] = *(const bf16x8*)((const char*)sA + aoff[m]);            \
    _Pragma("unroll") for (int n = 0; n < 4; ++n)                       \
        bv[n] = *(const bf16x8*)((const char*)sB + boff[n]);            \
    _Pragma("unroll") for (int m = 0; m < 4; ++m)                       \
        _Pragma("unroll") for (int n = 0; n < 4; ++n)                   \
            acc[m][n] = __builtin_amdgcn_mfma_f32_16x16x32_bf16(        \
                av[m], bv[n], acc[m][n], 0, 0, 0);                      \
  } while (0)

  LOADG(0, pa0, pa1, pb0, pb1);
  for (int ks = 0; ks < nK; ++ks) {
    __syncthreads();
    if (ks & 1) {
      STAGE(qa0, qa1, qb0, qb1);
      if (ks + 1 < nK) LOADG(ks + 1, pa0, pa1, pb0, pb1);
    } else {
      STAGE(pa0, pa1, pb0, pb1);
      if (ks + 1 < nK) LOADG(ks + 1, qa0, qa1, qb0, qb1);
    }
    __syncthreads();
    COMPUTE();
  }

  // epilogue: stage tile in LDS, then coalesced bf16x8 stores into the split half
  __syncthreads();
#pragma unroll
  for (int m = 0; m < 4; ++m) {
#pragma unroll
    for (int n = 0; n < 4; ++n) {
      int tc = wc * 64 + n * 16 + fr;
      float bv = ((col0 + tc) < nhalf) ? blo[col0 + tc] : bhi[col0 + tc - nhalf];
#pragma unroll
      for (int j = 0; j < 4; ++j) {
        int tr = wr * 64 + m * 16 + kq * 4 + j;
        smem[tr * ESTRIDE + tc] = f2b(acc[m][n][j] + bv);
      }
    }
  }
  __syncthreads();
  ushort* Cd = (col0 < nhalf) ? Clo : Chi;
  int cb0 = (col0 < nhalf) ? col0 : col0 - nhalf;
  int r0 = tid >> 4, cb = (tid & 15) * 8;
#pragma unroll
  for (int pass = 0; pass < 8; ++pass) {
    int r = pass * 16 + r0;
    int grow = row0 + r;
    if (grow < M) {
      bf16x8 vv = *(const bf16x8*)&smem[r * ESTRIDE + cb];
      *(bf16x8*)&Cd[(size_t)grow * nhalf + cb0 + cb] = vv;
    }
  }
#undef LOADG
#undef STAGE
#undef COMPUTE
}

// ---------------- GAT layer 1: dense xl [N][512] bf16, xr [N][512] bf16 ----------------
// 1024-thr blocks (test blocks/CU residency cap); scalarized CSR walk; 4-deep ring;
// score via TWO independent fma chains (even/odd) to halve dep depth.
__global__ __launch_bounds__(1024, 8) void k_gat1(
    const ushort* __restrict__ xl, const ushort* __restrict__ xr,
    const int* __restrict__ rowptr, const int* __restrict__ csr,
    const float* __restrict__ att, const float* __restrict__ bias,
    const float* __restrict__ lng, const float* __restrict__ lnb,
    ushort* __restrict__ out, int n) {
  int lane = threadIdx.x & 63;
  int wid = __builtin_amdgcn_readfirstlane((int)((blockIdx.x * blockDim.x + threadIdx.x) >> 6));
  if (wid >= n) return;
  int base = lane * 8;
  float xrv[8], a6[8], a4[8];
  {
    bf16x8 t = *(const bf16x8*)(xr + (size_t)wid * 512 + base);
    unpack8(t, xrv);
#pragma unroll
    for (int j = 0; j < 8; ++j) {
      float a = att[base + j] * LOG2E;
      a6[j] = 0.6f * a;
      a4[j] = 0.4f * a;
    }
  }
  float s = 0.f;
  float acc[8] = {};
  int e0 = rowptr[wid], e1 = rowptr[wid + 1];
  int last = e1 - 1;

#define LROW1(ROW) (*(const bf16x8*)(xl + (size_t)(ROW) * 512 + base))
  bf16x8 r0 = LROW1(csr[e0]);
  bf16x8 r1 = LROW1(csr[min(e0 + 1, last)]);
  bf16x8 r2 = LROW1(csr[min(e0 + 2, last)]);
  bf16x8 r3 = LROW1(csr[min(e0 + 3, last)]);

  for (int pp = e0; pp < e1; pp += 4) {
    int i0 = csr[min(pp + 4, last)], i1 = csr[min(pp + 5, last)];
    int i2 = csr[min(pp + 6, last)], i3 = csr[min(pp + 7, last)];
    bf16x8 c0 = r0, c1 = r1, c2 = r2, c3 = r3;
    r0 = LROW1(i0); r1 = LROW1(i1); r2 = LROW1(i2); r3 = LROW1(i3);
    float v0[8], v1[8], v2[8], v3[8];
    unpack8(c0, v0); unpack8(c1, v1); unpack8(c2, v2); unpack8(c3, v3);
    float p0a = 0.f, p0b = 0.f, p1a = 0.f, p1b = 0.f;
    float p2a = 0.f, p2b = 0.f, p3a = 0.f, p3b = 0.f;
#pragma unroll
    for (int q = 0; q < 4; ++q) {
      int ja = 2 * q, jb = 2 * q + 1;
      float t0a = v0[ja] + xrv[ja], t0b = v0[jb] + xrv[jb];
      float t1a = v1[ja] + xrv[ja], t1b = v1[jb] + xrv[jb];
      float t2a = v2[ja] + xrv[ja], t2b = v2[jb] + xrv[jb];
      float t3a = v3[ja] + xrv[ja], t3b = v3[jb] + xrv[jb];
      p0a = fmaf(a6[ja], t0a, fmaf(a4[ja], fabsf(t0a), p0a));
      p0b = fmaf(a6[jb], t0b, fmaf(a4[jb], fabsf(t0b), p0b));
      p1a = fmaf(a6[ja], t1a, fmaf(a4[ja], fabsf(t1a), p1a));
      p1b = fmaf(a6[jb], t1b, fmaf(a4[jb], fabsf(t1b), p1b));
      p2a = fmaf(a6[ja], t2a, fmaf(a4[ja], fabsf(t2a), p2a));
      p2b = fmaf(a6[jb], t2b, fmaf(a4[jb], fabsf(t2b), p2b));
      p3a = fmaf(a6[ja], t3a, fmaf(a4[ja], fabsf(t3a), p3a));
      p3b = fmaf(a6[jb], t3b, fmaf(a4[jb], fabsf(t3b), p3b));
    }
    float pe0 = dppsum16(p0a + p0b);
    float pe1 = dppsum16(p1a + p1b);
    float pe2 = dppsum16(p2a + p2b);
    float pe3 = dppsum16(p3a + p3b);
    float w0 = exp2f(pe0 - 8.f * LOG2E);
    float w1 = (pp + 1 <= last) ? exp2f(pe1 - 8.f * LOG2E) : 0.f;
    float w2 = (pp + 2 <= last) ? exp2f(pe2 - 8.f * LOG2E) : 0.f;
    float w3 = (pp + 3 <= last) ? exp2f(pe3 - 8.f * LOG2E) : 0.f;
    s += (w0 + w1) + (w2 + w3);
#pragma unroll
    for (int j = 0; j < 8; ++j) {
      float t = fmaf(w0, v0[j], acc[j]);
      t = fmaf(w1, v1[j], t);
      t = fmaf(w2, v2[j], t);
      acc[j] = fmaf(w3, v3[j], t);
    }
  }
#undef LROW1
  float inv = 1.f / s;
  float o[8];
#pragma unroll
  for (int j = 0; j < 8; ++j) o[j] = acc[j] * inv + bias[base + j];
  float sum = 0.f, sq = 0.f;
#pragma unroll
  for (int j = 0; j < 8; ++j) { sum += o[j]; sq += o[j] * o[j]; }
  sum = dppsum16(sum); sq = dppsum16(sq);
  sum += __shfl_xor(sum, 16); sq += __shfl_xor(sq, 16);
  sum += __shfl_xor(sum, 32); sq += __shfl_xor(sq, 32);
  float mean = sum * (1.f / 512.f);
  float var = fmaxf(sq * (1.f / 512.f) - mean * mean, 0.f);
  float rstd = rsqrtf(var + 1e-5f);
  bf16x8 ov;
#pragma unroll
  for (int j = 0; j < 8; ++j) {
    float y = (o[j] - mean) * rstd * lng[base + j] + lnb[base + j];
    y = y > 0.f ? y : __expf(y) - 1.f;   // ELU
    ov[j] = (short)f2b(y);
  }
  *(bf16x8*)&out[(size_t)wid * 512 + base] = ov;
}

// ---------------- GAT layer 2: dense xl2 [N][256] bf16, xr2 [N][256] -> bf16 h2 ----------------
__global__ __launch_bounds__(1024, 8) void k_gat2(
    const ushort* __restrict__ xl, const ushort* __restrict__ xr,
    const int* __restrict__ rowptr, const int* __restrict__ csr,
    const float* __restrict__ att, const float* __restrict__ bias,
    const float* __restrict__ lng, const float* __restrict__ lnb,
    ushort* __restrict__ out, int n) {
  int lane = threadIdx.x & 63;
  int wid = __builtin_amdgcn_readfirstlane((int)((blockIdx.x * blockDim.x + threadIdx.x) >> 6));
  if (wid >= n) return;
  int base = lane * 4;
  float xrv[4], a6[4], a4[4];
  {
    bf16x4 t = *(const bf16x4*)(xr + (size_t)wid * 256 + base);
    unpack4(t, xrv);
#pragma unroll
    for (int j = 0; j < 4; ++j) {
      float a = att[base + j] * LOG2E;
      a6[j] = 0.6f * a;
      a4[j] = 0.4f * a;
    }
  }
  float s = 0.f;
  float acc[4] = {};
  int e0 = rowptr[wid], e1 = rowptr[wid + 1];
  int last = e1 - 1;

#define LROW2(ROW) (*(const bf16x4*)(xl + (size_t)(ROW) * 256 + base))
  bf16x4 r0 = LROW2(csr[e0]);
  bf16x4 r1 = LROW2(csr[min(e0 + 1, last)]);
  bf16x4 r2 = LROW2(csr[min(e0 + 2, last)]);
  bf16x4 r3 = LROW2(csr[min(e0 + 3, last)]);

  for (int pp = e0; pp < e1; pp += 4) {
    int i0 = csr[min(pp + 4, last)], i1 = csr[min(pp + 5, last)];
    int i2 = csr[min(pp + 6, last)], i3 = csr[min(pp + 7, last)];
    bf16x4 c0 = r0, c1 = r1, c2 = r2, c3 = r3;
    r0 = LROW2(i0); r1 = LROW2(i1); r2 = LROW2(i2); r3 = LROW2(i3);
    float v0[4], v1[4], v2[4], v3[4];
    unpack4(c0, v0); unpack4(c1, v1); unpack4(c2, v2); unpack4(c3, v3);
    float p0a = 0.f, p0b = 0.f, p1a = 0.f, p1b = 0.f;
    float p2a = 0.f, p2b = 0.f, p3a = 0.f, p3b = 0.f;
#pragma unroll
    for (int q = 0; q < 2; ++q) {
      int ja = 2 * q, jb = 2 * q + 1;
      float t0a = v0[ja] + xrv[ja], t0b = v0[jb] + xrv[jb];
      float t1a = v1[ja] + xrv[ja], t1b = v1[jb] + xrv[jb];
      float t2a = v2[ja] + xrv[ja], t2b = v2[jb] + xrv[jb];
      float t3a = v3[ja] + xrv[ja], t3b = v3[jb] + xrv[jb];
      p0a = fmaf(a6[ja], t0a, fmaf(a4[ja], fabsf(t0a), p0a));
      p0b = fmaf(a6[jb], t0b, fmaf(a4[jb], fabsf(t0b), p0b));
      p1a = fmaf(a6[ja], t1a, fmaf(a4[ja], fabsf(t1a), p1a));
      p1b = fmaf(a6[jb], t1b, fmaf(a4[jb], fabsf(t1b), p1b));
      p2a = fmaf(a6[ja], t2a, fmaf(a4[ja], fabsf(t2a), p2a));
      p2b = fmaf(a6[jb], t2b, fmaf(a4[jb], fabsf(t2b), p2b));
      p3a = fmaf(a6[ja], t3a, fmaf(a4[ja], fabsf(t3a), p3a));
      p3b = fmaf(a6[jb], t3b, fmaf(a4[jb], fabsf(t3b), p3b));
    }
    float pe0 = dppsum16(p0a + p0b);
    float pe1 = dppsum16(p1a + p1b);
    float pe2 = dppsum16(p2a + p2b);
    float pe3 = dppsum16(p3a + p3b);
    pe0 += __shfl_xor(pe0, 16); pe1 += __shfl_xor(pe1, 16);
    pe2 += __shfl_xor(pe2, 16); pe3 += __shfl_xor(pe3, 16);
    pe0 += __shfl_xor(pe0, 32); pe1 += __shfl_xor(pe1, 32);
    pe2 += __shfl_xor(pe2, 32); pe3 += __shfl_xor(pe3, 32);
    float w0 = exp2f(pe0 - 8.f * LOG2E);
    float w1 = (pp + 1 <= last) ? exp2f(pe1 - 8.f * LOG2E) : 0.f;
    float w2 = (pp + 2 <= last) ? exp2f(pe2 - 8.f * LOG2E) : 0.f;
    float w3 = (pp + 3 <= last) ? exp2f(pe3 - 8.f * LOG2E) : 0.f;
    s += (w0 + w1) + (w2 + w3);
#pragma unroll
    for (int j = 0; j < 4; ++j) {
      float t = fmaf(w0, v0[j], acc[j]);
      t = fmaf(w1, v1[j], t);
      t = fmaf(w2, v2[j], t);
      acc[j] = fmaf(w3, v3[j], t);
    }
  }
#undef LROW2
  float inv = 1.f / s;
  float o[4];
#pragma unroll
  for (int j = 0; j < 4; ++j) o[j] = acc[j] * inv + bias[base + j];
  float sum = 0.f, sq = 0.f;
#pragma unroll
  for (int j = 0; j < 4; ++j) { sum += o[j]; sq += o[j] * o[j]; }
  sum = dppsum16(sum); sq = dppsum16(sq);
  sum += __shfl_xor(sum, 16); sq += __shfl_xor(sq, 16);
  sum += __shfl_xor(sum, 32); sq += __shfl_xor(sq, 32);
  float mean = sum * (1.f / 256.f);
  float var = fmaxf(sq * (1.f / 256.f) - mean * mean, 0.f);
  float rstd = rsqrtf(var + 1e-5f);
  bf16x4 ov;
#pragma unroll
  for (int j = 0; j < 4; ++j) {
    float y = (o[j] - mean) * rstd * lng[base + j] + lnb[base + j];
    y = y > 0.f ? y : __expf(y) - 1.f;
    ov[j] = (short)f2b(y);
  }
  *(bf16x4*)&out[(size_t)wid * 256 + base] = ov;
}

// ---------------- pooling (batch is sorted), 64-row chunks, bf16 input ----------------
__global__ __launch_bounds__(256) void k_pool(
    const ushort* __restrict__ h2, const int* __restrict__ batch,
    float* __restrict__ pooled, int* __restrict__ cnt, int n) {
  int c = threadIdx.x;  // 256 channels
  int n0 = blockIdx.x * 64;
  int n1 = min(n0 + 64, n);
  if (n0 >= n) return;
  float acc = 0.f;
  int cur = batch[n0];
  int cl = 0;
  for (int i = n0; i < n1; ++i) {
    int bb = batch[i];
    if (bb != cur) {
      atomicAdd(&pooled[cur * 256 + c], acc);
      if (c == 0) atomicAdd(&cnt[cur], cl);
      acc = 0.f; cl = 0; cur = bb;
    }
    acc += b2f(h2[(size_t)i * 256 + c]);
    cl++;
  }
  atomicAdd(&pooled[cur * 256 + c], acc);
  if (c == 0) atomicAdd(&cnt[cur], cl);
}

// ---------------- projection head ----------------
__global__ __launch_bounds__(512) void k_proj1(
    const float* __restrict__ pooled, const int* __restrict__ cnt,
    const float* __restrict__ W, const float* __restrict__ b,
    const float* __restrict__ lng, const float* __restrict__ lnb,
    float* __restrict__ hout) {
  __shared__ float row[256];
  __shared__ float red[16];
  int g = blockIdx.x, c = threadIdx.x;
  if (c < 256) {
    float cc = fmaxf((float)cnt[g], 1.f);
    row[c] = pooled[g * 256 + c] / cc;
  }
  __syncthreads();
  float acc = b[c];
#pragma unroll 4
  for (int k = 0; k < 256; ++k) acc += row[k] * W[k * 512 + c];
  float sum = acc, sq = acc * acc;
#pragma unroll
  for (int off = 1; off < 64; off <<= 1) {
    sum += __shfl_xor(sum, off);
    sq += __shfl_xor(sq, off);
  }
  int wv = threadIdx.x >> 6;
  if ((threadIdx.x & 63) == 0) { red[wv] = sum; red[8 + wv] = sq; }
  __syncthreads();
  float S = 0.f, Q = 0.f;
#pragma unroll
  for (int t = 0; t < 8; ++t) { S += red[t]; Q += red[8 + t]; }
  float mean = S * (1.f / 512.f);
  float var = fmaxf(Q * (1.f / 512.f) - mean * mean, 0.f);
  float rstd = rsqrtf(var + 1e-5f);
  float y = (acc - mean) * rstd * lng[c] + lnb[c];
  float ge = 0.5f * y * (1.f + erff(y * 0.70710678118654752f));  // exact gelu
  hout[g * 512 + c] = ge;
}

__global__ __launch_bounds__(512) void k_proj2(
    const float* __restrict__ h, const float* __restrict__ W,
    const float* __restrict__ b, float* __restrict__ out) {
  __shared__ float row[512];
  __shared__ float red[8];
  int g = blockIdx.x, c = threadIdx.x;
  row[c] = h[g * 512 + c];
  __syncthreads();
  float acc = b[c];
#pragma unroll 4
  for (int k = 0; k < 512; ++k) acc += row[k] * W[k * 512 + c];
  float sq = acc * acc;
#pragma unroll
  for (int off = 1; off < 64; off <<= 1) sq += __shfl_xor(sq, off);
  int wv = threadIdx.x >> 6;
  if ((threadIdx.x & 63) == 0) red[wv] = sq;
  __syncthreads();
  float S = 0.f;
#pragma unroll
  for (int t = 0; t < 8; ++t) S += red[t];
  float norm = fmaxf(sqrtf(S), 1e-12f);
  out[g * 512 + c] = acc / norm;
}

// ---------------- launch ----------------
extern "C" void kernel_launch(void* const* d_in, const int* in_sizes, int n_in,
                              void* d_out, int out_size, void* d_ws, size_t ws_size,
                              hipStream_t stream) {
  const float* x_cont = (const float*)d_in[0];
  const int* x_class  = (const int*)d_in[1];
  const int* x_pitch  = (const int*)d_in[2];
  const int* ei       = (const int*)d_in[3];
  const int* batch    = (const int*)d_in[4];
  const float* ctab = (const float*)d_in[5];
  const float* ptab = (const float*)d_in[6];
  const float* Wl1 = (const float*)d_in[7];
  const float* bl1 = (const float*)d_in[8];
  const float* Wr1 = (const float*)d_in[9];
  const float* br1 = (const float*)d_in[10];
  const float* att1 = (const float*)d_in[11];
  const float* bias1 = (const float*)d_in[12];
  const float* ln1g = (const float*)d_in[13];
  const float* ln1b = (const float*)d_in[14];
  const float* Wl2 = (const float*)d_in[15];
  const float* bl2 = (const float*)d_in[16];
  const float* Wr2 = (const float*)d_in[17];
  const float* br2 = (const float*)d_in[18];
  const float* att2 = (const float*)d_in[19];
  const float* bias2 = (const float*)d_in[20];
  const float* ln2g = (const float*)d_in[21];
  const float* ln2b = (const float*)d_in[22];
  const float* Wp1 = (const float*)d_in[23];
  const float* bp1 = (const float*)d_in[24];
  const float* lnpg = (const float*)d_in[25];
  const float* lnpb = (const float*)d_in[26];
  const float* Wp2 = (const float*)d_in[27];
  const float* bp2 = (const float*)d_in[28];
  float* out = (float*)d_out;
  (void)n_in; (void)out_size; (void)ws_size;

  int N = in_sizes[1];
  int E = in_sizes[3] / 2;
  int ET = E + N;
  int NB = cdiv(N, 256);  // scan blocks (<= 256)

  // ---- workspace layout (with aliasing) ----
  char* p = (char*)d_ws;
  ushort* xb   = (ushort*)p; p += (size_t)N * 160 * 2;
  ushort* W1t  = (ushort*)p; p += (size_t)1024 * 160 * 2;
  ushort* W2t  = (ushort*)p; p += (size_t)512 * 512 * 2;
  ushort* xl1  = (ushort*)p; p += (size_t)N * 512 * 2;   // dense gather table L1
  ushort* xr1  = (ushort*)p; p += (size_t)N * 512 * 2;   // also h2 (bf16 N*256)
  ushort* h1b  = (ushort*)p; p += (size_t)N * 512 * 2;   // gat1 out (bf16)
  float* pooled = (float*)p; p += (size_t)NG * 256 * 4;
  int* cnt     = (int*)p;    p += NG * 4;
  float* hproj = (float*)p;  p += (size_t)NG * 512 * 4;
  int* deg     = (int*)p;    p += (size_t)N * 4;
  int* fill    = (int*)p;    p += (size_t)N * 4;
  int* rowptr  = (int*)p;    p += (size_t)(N + 1) * 4;
  int* csr     = (int*)p;    p += (size_t)(ET + 8) * 4;  // +8 sentinel pads
  int* bsum    = (int*)p;    p += 256 * 4;
  int* boff    = (int*)p;    p += 256 * 4;
  ushort* xl2 = xl1;                         // dense [N][256] (xl1 dead after gat1)
  ushort* xr2 = xl1 + (size_t)N * 256;
  ushort* h2  = xr1;                         // bf16 [N][256]

  const int* esrc = ei;
  const int* edst = ei + E;

  hipMemsetAsync(deg, 0, (size_t)2 * N * sizeof(int), stream);
  hipMemsetAsync(pooled, 0, (size_t)NG * 256 * sizeof(float) + NG * sizeof(int), stream);

  int prep_total = N * 160 + 1024 * 160 + 512 * 512 + ET;
  k_prep<<<cdiv(prep_total, 256), 256, 0, stream>>>(
      x_cont, x_class, x_pitch, ctab, ptab, Wl1, Wr1, Wl2, Wr2, edst,
      xb, W1t, W2t, deg, N, E);
  k_bsum<<<NB, 256, 0, stream>>>(deg, bsum, N);
  k_scanb<<<1, 256, 0, stream>>>(bsum, boff, NB);
  k_scanc<<<NB, 256, 0, stream>>>(deg, boff, rowptr, N);
  k_scatter<<<cdiv(ET + 8, 256), 256, 0, stream>>>(esrc, edst, rowptr, fill, csr, E, N);

  dim3 g1(cdiv(N, GBM), 1024 / GBN);
  k_gemm_mfma<<<g1, 256, 0, stream>>>(xb, W1t, bl1, br1, 512, xl1, xr1, N, 160);
  k_gat1<<<cdiv(N * 64, 1024), 1024, 0, stream>>>(xl1, xr1, rowptr, csr, att1, bias1, ln1g, ln1b, h1b, N);

  dim3 g2(cdiv(N, GBM), 512 / GBN);
  k_gemm_mfma<<<g2, 256, 0, stream>>>(h1b, W2t, bl2, br2, 256, xl2, xr2, N, 512);
  k_gat2<<<cdiv(N * 64, 1024), 1024, 0, stream>>>(xl2, xr2, rowptr, csr, att2, bias2, ln2g, ln2b, h2, N);

  k_pool<<<cdiv(N, 64), 256, 0, stream>>>(h2, batch, pooled, cnt, N);
  k_proj1<<<NG, 512, 0, stream>>>(pooled, cnt, Wp1, bp1, lnpg, lnpb, hproj);
  k_proj2<<<NG, 512, 0, stream>>>(hproj, Wp2, bp2, out);
}

// Round 11
// 337.129 us; speedup vs baseline: 1.4748x; 1.4748x over previous
//
#include <hip/hip_runtime.h>
#include <math.h>

#define NG 64   // graphs

typedef short bf16x8 __attribute__((ext_vector_type(8)));
typedef short bf16x4 __attribute__((ext_vector_type(4)));
typedef float f32x4 __attribute__((ext_vector_type(4)));

#define LOG2E 1.4426950408889634f

static inline int cdiv(int a, int b) { return (a + b - 1) / b; }

__device__ inline ushort f2b(float f) {
  union { float f; uint u; } v; v.f = f;
  uint u = v.u;
  return (ushort)((u + 0x7fffu + ((u >> 16) & 1u)) >> 16);
}
__device__ inline float b2f(ushort h) {
  union { uint u; float f; } v; v.u = ((uint)h) << 16;
  return v.f;
}

__device__ __forceinline__ void unpack8(bf16x8 vb, float* v) {
  union { bf16x8 b; uint u[4]; } cv; cv.b = vb;
#pragma unroll
  for (int q = 0; q < 4; ++q) {
    union { uint u; float f; } lo, hi;
    lo.u = cv.u[q] << 16;
    hi.u = cv.u[q] & 0xffff0000u;
    v[2 * q] = lo.f; v[2 * q + 1] = hi.f;
  }
}
__device__ __forceinline__ void unpack4(bf16x4 vb, float* v) {
  union { bf16x4 b; uint u[2]; } cv; cv.b = vb;
#pragma unroll
  for (int q = 0; q < 2; ++q) {
    union { uint u; float f; } lo, hi;
    lo.u = cv.u[q] << 16;
    hi.u = cv.u[q] & 0xffff0000u;
    v[2 * q] = lo.f; v[2 * q + 1] = hi.f;
  }
}

// pure-VALU all-reduce (sum) within each 16-lane row via DPP row_ror
__device__ __forceinline__ float dppsum16(float x) {
  union { float f; int i; } a, b;
  a.f = x;
  b.i = __builtin_amdgcn_update_dpp(0, a.i, 0x121, 0xF, 0xF, true); a.f += b.f; // ror:1
  b.i = __builtin_amdgcn_update_dpp(0, a.i, 0x122, 0xF, 0xF, true); a.f += b.f; // ror:2
  b.i = __builtin_amdgcn_update_dpp(0, a.i, 0x124, 0xF, 0xF, true); a.f += b.f; // ror:4
  b.i = __builtin_amdgcn_update_dpp(0, a.i, 0x128, 0xF, 0xF, true); a.f += b.f; // ror:8
  return a.f;
}

// ---------------- fused prep: features + both weight transposes + degree hist ----------------
__global__ __launch_bounds__(256) void k_prep(
    const float* __restrict__ xc, const int* __restrict__ xcl,
    const int* __restrict__ xpi, const float* __restrict__ ctab,
    const float* __restrict__ ptab,
    const float* __restrict__ Wl1, const float* __restrict__ Wr1,
    const float* __restrict__ Wl2, const float* __restrict__ Wr2,
    const int* __restrict__ edst,
    ushort* __restrict__ xb, ushort* __restrict__ W1t, ushort* __restrict__ W2t,
    int* __restrict__ deg, int n, int E) {
  int t = blockIdx.x * blockDim.x + threadIdx.x;
  int T1 = n * 160;
  int T2 = T1 + 1024 * 160;
  int T3 = T2 + 512 * 512;
  int T4 = T3 + E + n;
  if (t < T1) {
    int node = t / 160, c = t % 160;
    float v;
    if (c < 6)        v = xc[node * 6 + c];
    else if (c < 70)  v = ctab[xcl[node] * 64 + (c - 6)];
    else if (c < 134) v = ptab[xpi[node] * 64 + (c - 70)];
    else              v = 0.f;
    xb[t] = f2b(v);
  } else if (t < T2) {
    int u = t - T1;
    int c = u / 160, k = u % 160;
    float v = 0.f;
    if (k < 134) v = (c < 512) ? Wl1[k * 512 + c] : Wr1[k * 512 + (c - 512)];
    W1t[u] = f2b(v);
  } else if (t < T3) {
    int u = t - T2;
    int c = u / 512, k = u % 512;
    float v = (c < 256) ? Wl2[k * 256 + c] : Wr2[k * 256 + (c - 256)];
    W2t[u] = f2b(v);
  } else if (t < T4) {
    int u = t - T3;
    if (u < E) atomicAdd(&deg[edst[u]], 1);
    else atomicAdd(&deg[u - E], 1);   // self loops
  }
}

// 3-phase scan
__global__ __launch_bounds__(256) void k_bsum(const int* __restrict__ deg,
                                              int* __restrict__ bsum, int n) {
  int i = blockIdx.x * 256 + threadIdx.x;
  int v = (i < n) ? deg[i] : 0;
#pragma unroll
  for (int off = 1; off < 64; off <<= 1) v += __shfl_xor(v, off);
  __shared__ int ws[4];
  if ((threadIdx.x & 63) == 0) ws[threadIdx.x >> 6] = v;
  __syncthreads();
  if (threadIdx.x == 0) bsum[blockIdx.x] = ws[0] + ws[1] + ws[2] + ws[3];
}

__global__ __launch_bounds__(256) void k_scanb(const int* __restrict__ bsum,
                                               int* __restrict__ boff, int nb) {
  int t = threadIdx.x, lane = t & 63;
  int v = (t < nb) ? bsum[t] : 0;
  int incl = v;
#pragma unroll
  for (int off = 1; off < 64; off <<= 1) {
    int u = __shfl_up(incl, off);
    if (lane >= off) incl += u;
  }
  __shared__ int wsum[4];
  if (lane == 63) wsum[t >> 6] = incl;
  __syncthreads();
  int add = 0;
  for (int w = 0; w < (t >> 6); ++w) add += wsum[w];
  if (t < nb) boff[t] = incl + add - v;  // exclusive
}

__global__ __launch_bounds__(256) void k_scanc(const int* __restrict__ deg,
                                               const int* __restrict__ boff,
                                               int* __restrict__ rowptr, int n) {
  int b = blockIdx.x, t = threadIdx.x, lane = t & 63;
  int i = b * 256 + t;
  int v = (i < n) ? deg[i] : 0;
  int incl = v;
#pragma unroll
  for (int off = 1; off < 64; off <<= 1) {
    int u = __shfl_up(incl, off);
    if (lane >= off) incl += u;
  }
  __shared__ int wsum[4];
  if (lane == 63) wsum[t >> 6] = incl;
  __syncthreads();
  int add = boff[b];
  for (int w = 0; w < (t >> 6); ++w) add += wsum[w];
  if (i < n) rowptr[i + 1] = incl + add;
  if (i == 0) rowptr[0] = 0;
}

__global__ __launch_bounds__(256) void k_scatter(
    const int* __restrict__ src, const int* __restrict__ dst,
    const int* __restrict__ rowptr, int* __restrict__ fill,
    int* __restrict__ csr, int E, int N) {
  int t = blockIdx.x * blockDim.x + threadIdx.x;
  int s, d;
  if (t < E) { s = src[t]; d = dst[t]; }
  else if (t < E + N) { s = t - E; d = t - E; }
  else if (t < E + N + 8) { csr[t] = 0; return; }
  else return;
  int pos = rowptr[d] + atomicAdd(&fill[d], 1);
  csr[pos] = s;
}

// ---------------- bf16 MFMA GEMM with SPLIT output: cols<nhalf -> Clo, else Chi ----------------
#define GBM 128
#define GBN 128
#define GBK 32
#define ESTRIDE 136
__device__ __forceinline__ int swzf(int r, int s) {
  return r * 64 + ((s * 16) ^ (((r >> 1) & 3) << 4));
}
__global__ __launch_bounds__(256) void k_gemm_mfma(
    const ushort* __restrict__ A, const ushort* __restrict__ Bt,
    const float* __restrict__ blo, const float* __restrict__ bhi, int nhalf,
    ushort* __restrict__ Clo, ushort* __restrict__ Chi, int M, int Kp) {
  __shared__ ushort smem[GBM * ESTRIDE];
  ushort* sA = smem;
  ushort* sB = smem + GBM * GBK;
  int tid = threadIdx.x;
  int lane = tid & 63, w = tid >> 6;
  int wr = w >> 1, wc = w & 1;
  int row0 = blockIdx.x * GBM, col0 = blockIdx.y * GBN;
  int nK = Kp / GBK;

  int rs = tid >> 2, ss = tid & 3;
  int wO0 = swzf(rs, ss);
  int wO1 = swzf(rs + 64, ss);
  bool okA0 = (row0 + rs) < M;
  bool okA1 = (row0 + rs + 64) < M;
  size_t baseA0 = (size_t)(row0 + rs) * Kp + ss * 8;
  size_t baseA1 = (size_t)(row0 + rs + 64) * Kp + ss * 8;
  size_t baseB0 = (size_t)(col0 + rs) * Kp + ss * 8;
  size_t baseB1 = (size_t)(col0 + rs + 64) * Kp + ss * 8;

  int fr = lane & 15, kq = lane >> 4;
  int aoff[4], boff[4];
#pragma unroll
  for (int m = 0; m < 4; ++m) {
    int ra = wr * 64 + m * 16 + fr;
    aoff[m] = ra * 64 + ((kq * 16) ^ (((ra >> 1) & 3) << 4));
    int rb = wc * 64 + m * 16 + fr;
    boff[m] = rb * 64 + ((kq * 16) ^ (((rb >> 1) & 3) << 4));
  }

  f32x4 acc[4][4] = {};
  bf16x8 zz = {};
  bf16x8 pa0, pa1, pb0, pb1, qa0, qa1, qb0, qb1;

#define LOADG(KS, RA0, RA1, RB0, RB1)                                   \
  do {                                                                  \
    const ushort* ap = A + (size_t)(KS) * GBK;                          \
    const ushort* bp = Bt + (size_t)(KS) * GBK;                         \
    RA0 = okA0 ? *(const bf16x8*)(ap + baseA0) : zz;                    \
    RA1 = okA1 ? *(const bf16x8*)(ap + baseA1) : zz;                    \
    RB0 = *(const bf16x8*)(bp + baseB0);                                \
    RB1 = *(const bf16x8*)(bp + baseB1);                                \
  } while (0)

#define STAGE(RA0, RA1, RB0, RB1)                                       \
  do {                                                                  \
    *(bf16x8*)((char*)sA + wO0) = RA0;                                  \
    *(bf16x8*)((char*)sA + wO1) = RA1;                                  \
    *(bf16x8*)((char*)sB + wO0) = RB0;                                  \
    *(bf16x8*)((char*)sB + wO1) = RB1;                                  \
  } while (0)

#define COMPUTE()                                                       \
  do {                                                                  \
    bf16x8 av[4], bv[4];                                                \
    _Pragma("unroll") for (int m = 0; m < 4; ++m)                       \
        av[m] = *(const bf16x8*)((const char*)sA + aoff[m]);            \
    _Pragma("unroll") for (int n = 0; n < 4; ++n)                       \
        bv[n] = *(const bf16x8*)((const char*)sB + boff[n]);            \
    _Pragma("unroll") for (int m = 0; m < 4; ++m)                       \
        _Pragma("unroll") for (int n = 0; n < 4; ++n)                   \
            acc[m][n] = __builtin_amdgcn_mfma_f32_16x16x32_bf16(        \
                av[m], bv[n], acc[m][n], 0, 0, 0);                      \
  } while (0)

  LOADG(0, pa0, pa1, pb0, pb1);
  for (int ks = 0; ks < nK; ++ks) {
    __syncthreads();
    if (ks & 1) {
      STAGE(qa0, qa1, qb0, qb1);
      if (ks + 1 < nK) LOADG(ks + 1, pa0, pa1, pb0, pb1);
    } else {
      STAGE(pa0, pa1, pb0, pb1);
      if (ks + 1 < nK) LOADG(ks + 1, qa0, qa1, qb0, qb1);
    }
    __syncthreads();
    COMPUTE();
  }

  // epilogue: stage tile in LDS, then coalesced bf16x8 stores into the split half
  __syncthreads();
#pragma unroll
  for (int m = 0; m < 4; ++m) {
#pragma unroll
    for (int n = 0; n < 4; ++n) {
      int tc = wc * 64 + n * 16 + fr;
      float bv = ((col0 + tc) < nhalf) ? blo[col0 + tc] : bhi[col0 + tc - nhalf];
#pragma unroll
      for (int j = 0; j < 4; ++j) {
        int tr = wr * 64 + m * 16 + kq * 4 + j;
        smem[tr * ESTRIDE + tc] = f2b(acc[m][n][j] + bv);
      }
    }
  }
  __syncthreads();
  ushort* Cd = (col0 < nhalf) ? Clo : Chi;
  int cb0 = (col0 < nhalf) ? col0 : col0 - nhalf;
  int r0 = tid >> 4, cb = (tid & 15) * 8;
#pragma unroll
  for (int pass = 0; pass < 8; ++pass) {
    int r = pass * 16 + r0;
    int grow = row0 + r;
    if (grow < M) {
      bf16x8 vv = *(const bf16x8*)&smem[r * ESTRIDE + cb];
      *(bf16x8*)&Cd[(size_t)grow * nhalf + cb0 + cb] = vv;
    }
  }
#undef LOADG
#undef STAGE
#undef COMPUTE
}

// ---------------- GAT layer 1: dense xl [N][512] bf16, xr [N][512] bf16 ----------------
// R9-proven config: 256 threads, (256,4), 40 VGPR, no spill. Scalarized CSR walk;
// SALU-clamped 4-deep ring; even/odd split score chains; w = exp2(pe - 8*log2e).
__global__ __launch_bounds__(256, 4) void k_gat1(
    const ushort* __restrict__ xl, const ushort* __restrict__ xr,
    const int* __restrict__ rowptr, const int* __restrict__ csr,
    const float* __restrict__ att, const float* __restrict__ bias,
    const float* __restrict__ lng, const float* __restrict__ lnb,
    ushort* __restrict__ out, int n) {
  int lane = threadIdx.x & 63;
  int wid = __builtin_amdgcn_readfirstlane((int)((blockIdx.x * blockDim.x + threadIdx.x) >> 6));
  if (wid >= n) return;
  int base = lane * 8;
  float xrv[8], a6[8], a4[8];
  {
    bf16x8 t = *(const bf16x8*)(xr + (size_t)wid * 512 + base);
    unpack8(t, xrv);
#pragma unroll
    for (int j = 0; j < 8; ++j) {
      float a = att[base + j] * LOG2E;
      a6[j] = 0.6f * a;
      a4[j] = 0.4f * a;
    }
  }
  float s = 0.f;
  float acc[8] = {};
  int e0 = rowptr[wid], e1 = rowptr[wid + 1];
  int last = e1 - 1;

#define LROW1(ROW) (*(const bf16x8*)(xl + (size_t)(ROW) * 512 + base))
  bf16x8 r0 = LROW1(csr[e0]);
  bf16x8 r1 = LROW1(csr[min(e0 + 1, last)]);
  bf16x8 r2 = LROW1(csr[min(e0 + 2, last)]);
  bf16x8 r3 = LROW1(csr[min(e0 + 3, last)]);

  for (int pp = e0; pp < e1; pp += 4) {
    int i0 = csr[min(pp + 4, last)], i1 = csr[min(pp + 5, last)];
    int i2 = csr[min(pp + 6, last)], i3 = csr[min(pp + 7, last)];
    bf16x8 c0 = r0, c1 = r1, c2 = r2, c3 = r3;
    r0 = LROW1(i0); r1 = LROW1(i1); r2 = LROW1(i2); r3 = LROW1(i3);
    float v0[8], v1[8], v2[8], v3[8];
    unpack8(c0, v0); unpack8(c1, v1); unpack8(c2, v2); unpack8(c3, v3);
    float p0a = 0.f, p0b = 0.f, p1a = 0.f, p1b = 0.f;
    float p2a = 0.f, p2b = 0.f, p3a = 0.f, p3b = 0.f;
#pragma unroll
    for (int q = 0; q < 4; ++q) {
      int ja = 2 * q, jb = 2 * q + 1;
      float t0a = v0[ja] + xrv[ja], t0b = v0[jb] + xrv[jb];
      float t1a = v1[ja] + xrv[ja], t1b = v1[jb] + xrv[jb];
      float t2a = v2[ja] + xrv[ja], t2b = v2[jb] + xrv[jb];
      float t3a = v3[ja] + xrv[ja], t3b = v3[jb] + xrv[jb];
      p0a = fmaf(a6[ja], t0a, fmaf(a4[ja], fabsf(t0a), p0a));
      p0b = fmaf(a6[jb], t0b, fmaf(a4[jb], fabsf(t0b), p0b));
      p1a = fmaf(a6[ja], t1a, fmaf(a4[ja], fabsf(t1a), p1a));
      p1b = fmaf(a6[jb], t1b, fmaf(a4[jb], fabsf(t1b), p1b));
      p2a = fmaf(a6[ja], t2a, fmaf(a4[ja], fabsf(t2a), p2a));
      p2b = fmaf(a6[jb], t2b, fmaf(a4[jb], fabsf(t2b), p2b));
      p3a = fmaf(a6[ja], t3a, fmaf(a4[ja], fabsf(t3a), p3a));
      p3b = fmaf(a6[jb], t3b, fmaf(a4[jb], fabsf(t3b), p3b));
    }
    float pe0 = dppsum16(p0a + p0b);
    float pe1 = dppsum16(p1a + p1b);
    float pe2 = dppsum16(p2a + p2b);
    float pe3 = dppsum16(p3a + p3b);
    float w0 = exp2f(pe0 - 8.f * LOG2E);
    float w1 = (pp + 1 <= last) ? exp2f(pe1 - 8.f * LOG2E) : 0.f;
    float w2 = (pp + 2 <= last) ? exp2f(pe2 - 8.f * LOG2E) : 0.f;
    float w3 = (pp + 3 <= last) ? exp2f(pe3 - 8.f * LOG2E) : 0.f;
    s += (w0 + w1) + (w2 + w3);
#pragma unroll
    for (int j = 0; j < 8; ++j) {
      float t = fmaf(w0, v0[j], acc[j]);
      t = fmaf(w1, v1[j], t);
      t = fmaf(w2, v2[j], t);
      acc[j] = fmaf(w3, v3[j], t);
    }
  }
#undef LROW1
  float inv = 1.f / s;
  float o[8];
#pragma unroll
  for (int j = 0; j < 8; ++j) o[j] = acc[j] * inv + bias[base + j];
  float sum = 0.f, sq = 0.f;
#pragma unroll
  for (int j = 0; j < 8; ++j) { sum += o[j]; sq += o[j] * o[j]; }
  sum = dppsum16(sum); sq = dppsum16(sq);
  sum += __shfl_xor(sum, 16); sq += __shfl_xor(sq, 16);
  sum += __shfl_xor(sum, 32); sq += __shfl_xor(sq, 32);
  float mean = sum * (1.f / 512.f);
  float var = fmaxf(sq * (1.f / 512.f) - mean * mean, 0.f);
  float rstd = rsqrtf(var + 1e-5f);
  bf16x8 ov;
#pragma unroll
  for (int j = 0; j < 8; ++j) {
    float y = (o[j] - mean) * rstd * lng[base + j] + lnb[base + j];
    y = y > 0.f ? y : __expf(y) - 1.f;   // ELU
    ov[j] = (short)f2b(y);
  }
  *(bf16x8*)&out[(size_t)wid * 512 + base] = ov;
}

// ---------------- GAT layer 2: dense xl2 [N][256] bf16, xr2 [N][256] -> bf16 h2 ----------------
__global__ __launch_bounds__(256, 4) void k_gat2(
    const ushort* __restrict__ xl, const ushort* __restrict__ xr,
    const int* __restrict__ rowptr, const int* __restrict__ csr,
    const float* __restrict__ att, const float* __restrict__ bias,
    const float* __restrict__ lng, const float* __restrict__ lnb,
    ushort* __restrict__ out, int n) {
  int lane = threadIdx.x & 63;
  int wid = __builtin_amdgcn_readfirstlane((int)((blockIdx.x * blockDim.x + threadIdx.x) >> 6));
  if (wid >= n) return;
  int base = lane * 4;
  float xrv[4], a6[4], a4[4];
  {
    bf16x4 t = *(const bf16x4*)(xr + (size_t)wid * 256 + base);
    unpack4(t, xrv);
#pragma unroll
    for (int j = 0; j < 4; ++j) {
      float a = att[base + j] * LOG2E;
      a6[j] = 0.6f * a;
      a4[j] = 0.4f * a;
    }
  }
  float s = 0.f;
  float acc[4] = {};
  int e0 = rowptr[wid], e1 = rowptr[wid + 1];
  int last = e1 - 1;

#define LROW2(ROW) (*(const bf16x4*)(xl + (size_t)(ROW) * 256 + base))
  bf16x4 r0 = LROW2(csr[e0]);
  bf16x4 r1 = LROW2(csr[min(e0 + 1, last)]);
  bf16x4 r2 = LROW2(csr[min(e0 + 2, last)]);
  bf16x4 r3 = LROW2(csr[min(e0 + 3, last)]);

  for (int pp = e0; pp < e1; pp += 4) {
    int i0 = csr[min(pp + 4, last)], i1 = csr[min(pp + 5, last)];
    int i2 = csr[min(pp + 6, last)], i3 = csr[min(pp + 7, last)];
    bf16x4 c0 = r0, c1 = r1, c2 = r2, c3 = r3;
    r0 = LROW2(i0); r1 = LROW2(i1); r2 = LROW2(i2); r3 = LROW2(i3);
    float v0[4], v1[4], v2[4], v3[4];
    unpack4(c0, v0); unpack4(c1, v1); unpack4(c2, v2); unpack4(c3, v3);
    float p0a = 0.f, p0b = 0.f, p1a = 0.f, p1b = 0.f;
    float p2a = 0.f, p2b = 0.f, p3a = 0.f, p3b = 0.f;
#pragma unroll
    for (int q = 0; q < 2; ++q) {
      int ja = 2 * q, jb = 2 * q + 1;
      float t0a = v0[ja] + xrv[ja], t0b = v0[jb] + xrv[jb];
      float t1a = v1[ja] + xrv[ja], t1b = v1[jb] + xrv[jb];
      float t2a = v2[ja] + xrv[ja], t2b = v2[jb] + xrv[jb];
      float t3a = v3[ja] + xrv[ja], t3b = v3[jb] + xrv[jb];
      p0a = fmaf(a6[ja], t0a, fmaf(a4[ja], fabsf(t0a), p0a));
      p0b = fmaf(a6[jb], t0b, fmaf(a4[jb], fabsf(t0b), p0b));
      p1a = fmaf(a6[ja], t1a, fmaf(a4[ja], fabsf(t1a), p1a));
      p1b = fmaf(a6[jb], t1b, fmaf(a4[jb], fabsf(t1b), p1b));
      p2a = fmaf(a6[ja], t2a, fmaf(a4[ja], fabsf(t2a), p2a));
      p2b = fmaf(a6[jb], t2b, fmaf(a4[jb], fabsf(t2b), p2b));
      p3a = fmaf(a6[ja], t3a, fmaf(a4[ja], fabsf(t3a), p3a));
      p3b = fmaf(a6[jb], t3b, fmaf(a4[jb], fabsf(t3b), p3b));
    }
    float pe0 = dppsum16(p0a + p0b);
    float pe1 = dppsum16(p1a + p1b);
    float pe2 = dppsum16(p2a + p2b);
    float pe3 = dppsum16(p3a + p3b);
    pe0 += __shfl_xor(pe0, 16); pe1 += __shfl_xor(pe1, 16);
    pe2 += __shfl_xor(pe2, 16); pe3 += __shfl_xor(pe3, 16);
    pe0 += __shfl_xor(pe0, 32); pe1 += __shfl_xor(pe1, 32);
    pe2 += __shfl_xor(pe2, 32); pe3 += __shfl_xor(pe3, 32);
    float w0 = exp2f(pe0 - 8.f * LOG2E);
    float w1 = (pp + 1 <= last) ? exp2f(pe1 - 8.f * LOG2E) : 0.f;
    float w2 = (pp + 2 <= last) ? exp2f(pe2 - 8.f * LOG2E) : 0.f;
    float w3 = (pp + 3 <= last) ? exp2f(pe3 - 8.f * LOG2E) : 0.f;
    s += (w0 + w1) + (w2 + w3);
#pragma unroll
    for (int j = 0; j < 4; ++j) {
      float t = fmaf(w0, v0[j], acc[j]);
      t = fmaf(w1, v1[j], t);
      t = fmaf(w2, v2[j], t);
      acc[j] = fmaf(w3, v3[j], t);
    }
  }
#undef LROW2
  float inv = 1.f / s;
  float o[4];
#pragma unroll
  for (int j = 0; j < 4; ++j) o[j] = acc[j] * inv + bias[base + j];
  float sum = 0.f, sq = 0.f;
#pragma unroll
  for (int j = 0; j < 4; ++j) { sum += o[j]; sq += o[j] * o[j]; }
  sum = dppsum16(sum); sq = dppsum16(sq);
  sum += __shfl_xor(sum, 16); sq += __shfl_xor(sq, 16);
  sum += __shfl_xor(sum, 32); sq += __shfl_xor(sq, 32);
  float mean = sum * (1.f / 256.f);
  float var = fmaxf(sq * (1.f / 256.f) - mean * mean, 0.f);
  float rstd = rsqrtf(var + 1e-5f);
  bf16x4 ov;
#pragma unroll
  for (int j = 0; j < 4; ++j) {
    float y = (o[j] - mean) * rstd * lng[base + j] + lnb[base + j];
    y = y > 0.f ? y : __expf(y) - 1.f;
    ov[j] = (short)f2b(y);
  }
  *(bf16x4*)&out[(size_t)wid * 256 + base] = ov;
}

// ---------------- pooling (batch is sorted), 64-row chunks, bf16 input ----------------
__global__ __launch_bounds__(256) void k_pool(
    const ushort* __restrict__ h2, const int* __restrict__ batch,
    float* __restrict__ pooled, int* __restrict__ cnt, int n) {
  int c = threadIdx.x;  // 256 channels
  int n0 = blockIdx.x * 64;
  int n1 = min(n0 + 64, n);
  if (n0 >= n) return;
  float acc = 0.f;
  int cur = batch[n0];
  int cl = 0;
  for (int i = n0; i < n1; ++i) {
    int bb = batch[i];
    if (bb != cur) {
      atomicAdd(&pooled[cur * 256 + c], acc);
      if (c == 0) atomicAdd(&cnt[cur], cl);
      acc = 0.f; cl = 0; cur = bb;
    }
    acc += b2f(h2[(size_t)i * 256 + c]);
    cl++;
  }
  atomicAdd(&pooled[cur * 256 + c], acc);
  if (c == 0) atomicAdd(&cnt[cur], cl);
}

// ---------------- projection head ----------------
__global__ __launch_bounds__(512) void k_proj1(
    const float* __restrict__ pooled, const int* __restrict__ cnt,
    const float* __restrict__ W, const float* __restrict__ b,
    const float* __restrict__ lng, const float* __restrict__ lnb,
    float* __restrict__ hout) {
  __shared__ float row[256];
  __shared__ float red[16];
  int g = blockIdx.x, c = threadIdx.x;
  if (c < 256) {
    float cc = fmaxf((float)cnt[g], 1.f);
    row[c] = pooled[g * 256 + c] / cc;
  }
  __syncthreads();
  float acc = b[c];
#pragma unroll 4
  for (int k = 0; k < 256; ++k) acc += row[k] * W[k * 512 + c];
  float sum = acc, sq = acc * acc;
#pragma unroll
  for (int off = 1; off < 64; off <<= 1) {
    sum += __shfl_xor(sum, off);
    sq += __shfl_xor(sq, off);
  }
  int wv = threadIdx.x >> 6;
  if ((threadIdx.x & 63) == 0) { red[wv] = sum; red[8 + wv] = sq; }
  __syncthreads();
  float S = 0.f, Q = 0.f;
#pragma unroll
  for (int t = 0; t < 8; ++t) { S += red[t]; Q += red[8 + t]; }
  float mean = S * (1.f / 512.f);
  float var = fmaxf(Q * (1.f / 512.f) - mean * mean, 0.f);
  float rstd = rsqrtf(var + 1e-5f);
  float y = (acc - mean) * rstd * lng[c] + lnb[c];
  float ge = 0.5f * y * (1.f + erff(y * 0.70710678118654752f));  // exact gelu
  hout[g * 512 + c] = ge;
}

__global__ __launch_bounds__(512) void k_proj2(
    const float* __restrict__ h, const float* __restrict__ W,
    const float* __restrict__ b, float* __restrict__ out) {
  __shared__ float row[512];
  __shared__ float red[8];
  int g = blockIdx.x, c = threadIdx.x;
  row[c] = h[g * 512 + c];
  __syncthreads();
  float acc = b[c];
#pragma unroll 4
  for (int k = 0; k < 512; ++k) acc += row[k] * W[k * 512 + c];
  float sq = acc * acc;
#pragma unroll
  for (int off = 1; off < 64; off <<= 1) sq += __shfl_xor(sq, off);
  int wv = threadIdx.x >> 6;
  if ((threadIdx.x & 63) == 0) red[wv] = sq;
  __syncthreads();
  float S = 0.f;
#pragma unroll
  for (int t = 0; t < 8; ++t) S += red[t];
  float norm = fmaxf(sqrtf(S), 1e-12f);
  out[g * 512 + c] = acc / norm;
}

// ---------------- launch ----------------
extern "C" void kernel_launch(void* const* d_in, const int* in_sizes, int n_in,
                              void* d_out, int out_size, void* d_ws, size_t ws_size,
                              hipStream_t stream) {
  const float* x_cont = (const float*)d_in[0];
  const int* x_class  = (const int*)d_in[1];
  const int* x_pitch  = (const int*)d_in[2];
  const int* ei       = (const int*)d_in[3];
  const int* batch    = (const int*)d_in[4];
  const float* ctab = (const float*)d_in[5];
  const float* ptab = (const float*)d_in[6];
  const float* Wl1 = (const float*)d_in[7];
  const float* bl1 = (const float*)d_in[8];
  const float* Wr1 = (const float*)d_in[9];
  const float* br1 = (const float*)d_in[10];
  const float* att1 = (const float*)d_in[11];
  const float* bias1 = (const float*)d_in[12];
  const float* ln1g = (const float*)d_in[13];
  const float* ln1b = (const float*)d_in[14];
  const float* Wl2 = (const float*)d_in[15];
  const float* bl2 = (const float*)d_in[16];
  const float* Wr2 = (const float*)d_in[17];
  const float* br2 = (const float*)d_in[18];
  const float* att2 = (const float*)d_in[19];
  const float* bias2 = (const float*)d_in[20];
  const float* ln2g = (const float*)d_in[21];
  const float* ln2b = (const float*)d_in[22];
  const float* Wp1 = (const float*)d_in[23];
  const float* bp1 = (const float*)d_in[24];
  const float* lnpg = (const float*)d_in[25];
  const float* lnpb = (const float*)d_in[26];
  const float* Wp2 = (const float*)d_in[27];
  const float* bp2 = (const float*)d_in[28];
  float* out = (float*)d_out;
  (void)n_in; (void)out_size; (void)ws_size;

  int N = in_sizes[1];
  int E = in_sizes[3] / 2;
  int ET = E + N;
  int NB = cdiv(N, 256);  // scan blocks (<= 256)

  // ---- workspace layout (with aliasing) ----
  char* p = (char*)d_ws;
  ushort* xb   = (ushort*)p; p += (size_t)N * 160 * 2;
  ushort* W1t  = (ushort*)p; p += (size_t)1024 * 160 * 2;
  ushort* W2t  = (ushort*)p; p += (size_t)512 * 512 * 2;
  ushort* xl1  = (ushort*)p; p += (size_t)N * 512 * 2;   // dense gather table L1
  ushort* xr1  = (ushort*)p; p += (size_t)N * 512 * 2;   // also h2 (bf16 N*256)
  ushort* h1b  = (ushort*)p; p += (size_t)N * 512 * 2;   // gat1 out (bf16)
  float* pooled = (float*)p; p += (size_t)NG * 256 * 4;
  int* cnt     = (int*)p;    p += NG * 4;
  float* hproj = (float*)p;  p += (size_t)NG * 512 * 4;
  int* deg     = (int*)p;    p += (size_t)N * 4;
  int* fill    = (int*)p;    p += (size_t)N * 4;
  int* rowptr  = (int*)p;    p += (size_t)(N + 1) * 4;
  int* csr     = (int*)p;    p += (size_t)(ET + 8) * 4;  // +8 sentinel pads
  int* bsum    = (int*)p;    p += 256 * 4;
  int* boff    = (int*)p;    p += 256 * 4;
  ushort* xl2 = xl1;                         // dense [N][256] (xl1 dead after gat1)
  ushort* xr2 = xl1 + (size_t)N * 256;
  ushort* h2  = xr1;                         // bf16 [N][256]

  const int* esrc = ei;
  const int* edst = ei + E;

  hipMemsetAsync(deg, 0, (size_t)2 * N * sizeof(int), stream);
  hipMemsetAsync(pooled, 0, (size_t)NG * 256 * sizeof(float) + NG * sizeof(int), stream);

  int prep_total = N * 160 + 1024 * 160 + 512 * 512 + ET;
  k_prep<<<cdiv(prep_total, 256), 256, 0, stream>>>(
      x_cont, x_class, x_pitch, ctab, ptab, Wl1, Wr1, Wl2, Wr2, edst,
      xb, W1t, W2t, deg, N, E);
  k_bsum<<<NB, 256, 0, stream>>>(deg, bsum, N);
  k_scanb<<<1, 256, 0, stream>>>(bsum, boff, NB);
  k_scanc<<<NB, 256, 0, stream>>>(deg, boff, rowptr, N);
  k_scatter<<<cdiv(ET + 8, 256), 256, 0, stream>>>(esrc, edst, rowptr, fill, csr, E, N);

  dim3 g1(cdiv(N, GBM), 1024 / GBN);
  k_gemm_mfma<<<g1, 256, 0, stream>>>(xb, W1t, bl1, br1, 512, xl1, xr1, N, 160);
  k_gat1<<<cdiv(N * 64, 256), 256, 0, stream>>>(xl1, xr1, rowptr, csr, att1, bias1, ln1g, ln1b, h1b, N);

  dim3 g2(cdiv(N, GBM), 512 / GBN);
  k_gemm_mfma<<<g2, 256, 0, stream>>>(h1b, W2t, bl2, br2, 256, xl2, xr2, N, 512);
  k_gat2<<<cdiv(N * 64, 256), 256, 0, stream>>>(xl2, xr2, rowptr, csr, att2, bias2, ln2g, ln2b, h2, N);

  k_pool<<<cdiv(N, 64), 256, 0, stream>>>(h2, batch, pooled, cnt, N);
  k_proj1<<<NG, 512, 0, stream>>>(pooled, cnt, Wp1, bp1, lnpg, lnpb, hproj);
  k_proj2<<<NG, 512, 0, stream>>>(hproj, Wp2, bp2, out);
}